// Round 8
// baseline (268.316 us; speedup 1.0000x reference)
//
#include <hip/hip_runtime.h>
#include <hip/hip_bf16.h>
#include <math.h>

#define LDIM 4096
#define NROWS 8192
#define NOUT 512

static const float SQRT_HALF_F = 0.70710678118654752440f;

typedef __attribute__((ext_vector_type(8))) short short8;
typedef __attribute__((ext_vector_type(4))) float f32x4;
typedef __attribute__((ext_vector_type(8))) unsigned short u16x8;
typedef __attribute__((ext_vector_type(4))) unsigned short u16x4;
typedef __attribute__((ext_vector_type(2))) unsigned short u16x2;

// ws layout
#define AM_OFF   0ull                         // bf16 masked A: 8192*4096*2 = 67108864
#define WT_OFF   67108864ull                  // bf16 Wt (N x K): 512*4096*2 = 4194304
#define PART_OFF (WT_OFF + 4194304ull)        // double[8192*2] partials
#define THR_OFF  (PART_OFF + 131072ull)       // float[1]

__device__ inline unsigned short f2bf(float f) {
  union { float f; unsigned u; } v; v.f = f;
  unsigned r = (v.u + 0x7fffu + ((v.u >> 16) & 1u)) >> 16;
  return (unsigned short)r;
}

__device__ inline unsigned short mcvt(float f, float thr) {
  return f2bf((fabsf(f) > thr) ? f : 0.0f);
}

__device__ inline void async16(void* l, const void* g) {
  __builtin_amdgcn_global_load_lds((const __attribute__((address_space(1))) void*)g,
                                   (__attribute__((address_space(3))) void*)l, 16, 0, 0);
}

// ---------------- Kernel 1: Haar stats (blocks 0..8191) + W convert (tail) ----
__global__ __launch_bounds__(256) void haar1_kernel(const float* __restrict__ x,
                                                    double* __restrict__ partials,
                                                    const float* __restrict__ W,
                                                    unsigned short* __restrict__ Wt) {
  if (blockIdx.x >= NROWS) {
    // ---- fused wcvt: W (K x N fp32) -> Wt (N x K bf16) ----
    __shared__ float tile[32][33];
    const int wb = blockIdx.x - NROWS;
    const int bx = wb & 15;        // n tile (16)
    const int by = wb >> 4;        // k tile (128)
    const int tx = threadIdx.x & 31, ty = threadIdx.x >> 5;
#pragma unroll
    for (int j = 0; j < 4; ++j)
      tile[ty + j * 8][tx] = W[(size_t)(by * 32 + ty + j * 8) * NOUT + bx * 32 + tx];
    __syncthreads();
#pragma unroll
    for (int j = 0; j < 4; ++j)
      Wt[(size_t)(bx * 32 + ty + j * 8) * LDIM + by * 32 + tx] = f2bf(tile[tx][ty + j * 8]);
    return;
  }

  __shared__ double red[8];
  const int row = blockIdx.x;
  const int t = threadIdx.x;
  const float S = SQRT_HALF_F;

  const float4* xr = (const float4*)(x + (size_t)row * LDIM) + 4 * t;
  float v[16];
#pragma unroll
  for (int k = 0; k < 4; ++k) {
    float4 q = xr[k];
    v[4 * k] = q.x; v[4 * k + 1] = q.y; v[4 * k + 2] = q.z; v[4 * k + 3] = q.w;
  }

  double sa = 0.0, sq = 0.0;
  float a1[8], a2[4], a3[2], a4;
#pragma unroll
  for (int j = 0; j < 8; ++j) {
    float d = (v[2 * j] - v[2 * j + 1]) * S;
    a1[j] = (v[2 * j] + v[2 * j + 1]) * S;
    sa += (double)fabsf(d); sq += (double)d * (double)d;
  }
#pragma unroll
  for (int j = 0; j < 4; ++j) {
    float d = (a1[2 * j] - a1[2 * j + 1]) * S;
    a2[j] = (a1[2 * j] + a1[2 * j + 1]) * S;
    sa += (double)fabsf(d); sq += (double)d * (double)d;
  }
#pragma unroll
  for (int j = 0; j < 2; ++j) {
    float d = (a2[2 * j] - a2[2 * j + 1]) * S;
    a3[j] = (a2[2 * j] + a2[2 * j + 1]) * S;
    sa += (double)fabsf(d); sq += (double)d * (double)d;
  }
  {
    float d = (a3[0] - a3[1]) * S;
    a4 = (a3[0] + a3[1]) * S;
    sa += (double)fabsf(d); sq += (double)d * (double)d;
  }
  {
    float other = __shfl_xor(a4, 1, 64);
    if ((t & 1) == 0) {
      float d = (a4 - other) * S, ap = (a4 + other) * S;
      sa += (double)fabsf(d) + (double)fabsf(ap);
      sq += (double)d * (double)d + (double)ap * (double)ap;
    }
  }

  const int lane = t & 63, wid = t >> 6;
#pragma unroll
  for (int off = 32; off > 0; off >>= 1) {
    sa += __shfl_down(sa, off, 64);
    sq += __shfl_down(sq, off, 64);
  }
  if (lane == 0) { red[wid] = sa; red[4 + wid] = sq; }
  __syncthreads();
  if (t == 0) {
    partials[2 * (size_t)row + 0] = red[0] + red[1] + red[2] + red[3];
    partials[2 * (size_t)row + 1] = red[4] + red[5] + red[6] + red[7];
  }
}

// ---------------- Kernel 2: reduce partials -> threshold ----------------
__global__ __launch_bounds__(1024) void thr_kernel(const double* __restrict__ partials,
                                                   float* __restrict__ thr) {
  __shared__ double red[32];
  const int tid = threadIdx.x;
  double sa = 0.0, sq = 0.0;
#pragma unroll
  for (int k = 0; k < NROWS / 1024; ++k) {
    int i = tid + k * 1024;
    sa += partials[2 * i + 0];
    sq += partials[2 * i + 1];
  }
  const int lane = tid & 63, wid = tid >> 6;
#pragma unroll
  for (int off = 32; off > 0; off >>= 1) {
    sa += __shfl_down(sa, off, 64);
    sq += __shfl_down(sq, off, 64);
  }
  if (lane == 0) { red[wid] = sa; red[16 + wid] = sq; }
  __syncthreads();
  if (tid == 0) {
    double s = 0.0, q = 0.0;
#pragma unroll
    for (int i = 0; i < 16; ++i) { s += red[i]; q += red[16 + i]; }
    const double n = (double)NROWS * (double)LDIM;
    double mean = s / n;
    double var = (q - s * s / n) / (n - 1.0);
    *thr = (float)(mean + sqrt(var));
  }
}

// ---------------- Kernel 3: Haar recompute + mask + bf16 write ----------------
__global__ __launch_bounds__(256) void haar2_kernel(const float* __restrict__ x,
                                                    const float* __restrict__ thrp,
                                                    unsigned short* __restrict__ Am) {
  const float thr = *thrp;
  const int row = blockIdx.x;
  const int t = threadIdx.x;
  const float S = SQRT_HALF_F;

  const float4* xr = (const float4*)(x + (size_t)row * LDIM) + 4 * t;
  float v[16];
#pragma unroll
  for (int k = 0; k < 4; ++k) {
    float4 q = xr[k];
    v[4 * k] = q.x; v[4 * k + 1] = q.y; v[4 * k + 2] = q.z; v[4 * k + 3] = q.w;
  }

  unsigned short* orow = Am + (size_t)row * LDIM;
  float a1[8], a2[4], a3[2], a4;

  u16x8 d1;
#pragma unroll
  for (int j = 0; j < 8; ++j) {
    float d = (v[2 * j] - v[2 * j + 1]) * S;
    a1[j] = (v[2 * j] + v[2 * j + 1]) * S;
    d1[j] = mcvt(d, thr);
  }
  *(u16x8*)(orow + 2048 + 8 * t) = d1;

  u16x4 d2;
#pragma unroll
  for (int j = 0; j < 4; ++j) {
    float d = (a1[2 * j] - a1[2 * j + 1]) * S;
    a2[j] = (a1[2 * j] + a1[2 * j + 1]) * S;
    d2[j] = mcvt(d, thr);
  }
  *(u16x4*)(orow + 1024 + 4 * t) = d2;

  u16x2 d3;
#pragma unroll
  for (int j = 0; j < 2; ++j) {
    float d = (a2[2 * j] - a2[2 * j + 1]) * S;
    a3[j] = (a2[2 * j] + a2[2 * j + 1]) * S;
    d3[j] = mcvt(d, thr);
  }
  *(u16x2*)(orow + 512 + 2 * t) = d3;

  {
    float d = (a3[0] - a3[1]) * S;
    a4 = (a3[0] + a3[1]) * S;
    orow[256 + t] = mcvt(d, thr);
  }
  {
    float other = __shfl_xor(a4, 1, 64);
    if ((t & 1) == 0) {
      float d = (a4 - other) * S, ap = (a4 + other) * S;
      orow[128 + t / 2] = mcvt(d, thr);
      orow[t / 2] = mcvt(ap, thr);
    }
  }
}

// ---------------- Kernel 4: bf16 MFMA GEMM + ReLU, 512 threads ----------------
// C[8192x512] = relu( Am @ Wt^T ). Round-12 structure.
// Ledger: R1 53us; R2/R5 (2w/SIMD) +12; R4 (B gather) +88; R7 (-25% LDS
// reads, VGPR-safe) NULL -> LDS-read throughput is NOT the limit. Remaining
// model: per-iteration critical path = compute (~450cy) + vmcnt(0) drain
// (~200-400cy for loads issued only a compute-phase earlier) + barrier,
// poorly overlapped between the 2 co-resident blocks.
// THIS ROUND (single change vs R7): 3-buffer staging + counted vmcnt(3)
// (T4). Steady state: wave has 6 loads outstanding (tiles t+1, t+2); waits
// until 3 remain -> waits only for loads issued a FULL iteration (~800+cy)
// ago, i.e. ~0 wait. Buffer rotation validated in R6 (passed). LDS 72 KB
// -> still 2 blk/CU. Compute mapping unchanged from R7: 8 waves = 4 tm x
// 2 kh, wave tile 32m x 64n over K=32 half, acc 32 VGPR, K-half LDS reduce
// at end (scratch aliases As[0]).
#define GEMM_COMPUTE(ASB, BSB)                                                        \
  {                                                                                   \
    short8 af[2], bf[4];                                                              \
    _Pragma("unroll")                                                                 \
    for (int mi = 0; mi < 2; ++mi) {                                                  \
      const int arow = tm * 32 + mi * 16 + l15;                                       \
      af[mi] = *(const short8*)&(ASB)[arow * 64 + (((kh * 4 + quad) ^ (arow & 7)) * 8)]; \
    }                                                                                 \
    _Pragma("unroll")                                                                 \
    for (int ni = 0; ni < 4; ++ni) {                                                  \
      const int brow = ni * 16 + l15;                                                 \
      bf[ni] = *(const short8*)&(BSB)[brow * 64 + (((kh * 4 + quad) ^ (brow & 7)) * 8)]; \
    }                                                                                 \
    _Pragma("unroll")                                                                 \
    for (int mi = 0; mi < 2; ++mi)                                                    \
      _Pragma("unroll")                                                               \
      for (int ni = 0; ni < 4; ++ni)                                                  \
        acc[mi][ni] = __builtin_amdgcn_mfma_f32_16x16x32_bf16(af[mi], bf[ni],         \
                                                              acc[mi][ni], 0, 0, 0);  \
  }

__global__ __launch_bounds__(512) void gemm_kernel(const unsigned short* __restrict__ Am,
                                                   const unsigned short* __restrict__ Wt,
                                                   float* __restrict__ out) {
  __shared__ __align__(16) unsigned short As[3][128 * 64];  // 48 KB
  __shared__ __align__(16) unsigned short Bs[3][64 * 64];   // 24 KB

  const int tid = threadIdx.x;
  const int lane = tid & 63, w = tid >> 6;      // 8 waves
  const int quad = lane >> 4, l15 = lane & 15;
  const int tm = w >> 1;                         // m-position: rows tm*32..+32
  const int kh = w & 1;                          // K-half of BK=64

  const int id = blockIdx.x;                    // grid 512
  const int xcd = id & 7, slot = id >> 3;
  const int nblk = slot & 7;
  const int mblk = (slot >> 3) * 8 + xcd;
  const int n0 = nblk * 64, m0 = mblk * 128;

  f32x4 acc[2][4] = {};   // wave tile 32m x 64n: frags (mi, ni)

  const int rl = lane >> 3;            // row within an 8-row DMA group
  const int cg = (lane & 7) ^ rl;      // XOR-swizzled source chunk index
  const unsigned short* AgBase = Am + (size_t)(m0 + rl) * LDIM + cg * 8;
  const unsigned short* BgBase = Wt + (size_t)(n0 + rl) * LDIM + cg * 8;

  // per-wave STAGE of one K-tile (3 async16): A 16 groups of 8 rows (2/wave),
  // B 8 groups (1/wave).
#define GEMM_STAGE(buf, k0)                                                            \
  {                                                                                    \
    _Pragma("unroll")                                                                  \
    for (int j = 0; j < 2; ++j)                                                        \
      async16(&As[buf][(w * 2 + j) * 512], AgBase + (size_t)((w * 2 + j) * 8) * LDIM + (k0)); \
    async16(&Bs[buf][w * 512], BgBase + (size_t)(w * 8) * LDIM + (k0));                \
  }

  // prologue: stage tiles 0,1; wait until only tile-1's 3 loads remain
  GEMM_STAGE(0, 0);
  GEMM_STAGE(1, 64);
  asm volatile("s_waitcnt vmcnt(3)" ::: "memory");
  __builtin_amdgcn_s_barrier();
  __builtin_amdgcn_sched_barrier(0);

  int ib0 = 0, ib1 = 1, ib2 = 2;
  for (int t = 0; t < (LDIM / 64) - 2; ++t) {
    GEMM_STAGE(ib2, (t + 2) * 64);     // tile t+2 issued; 6 outstanding
    GEMM_COMPUTE(As[ib0], Bs[ib0]);    // compute tile t
    asm volatile("s_waitcnt vmcnt(3)" ::: "memory");   // tile t+1 landed
    __builtin_amdgcn_s_barrier();
    __builtin_amdgcn_sched_barrier(0);
    const int tmp = ib0; ib0 = ib1; ib1 = ib2; ib2 = tmp;
  }
  // tile 62 (complete per last loop vmcnt+barrier)
  GEMM_COMPUTE(As[ib0], Bs[ib0]);
  asm volatile("s_waitcnt vmcnt(0)" ::: "memory");     // tile 63 drains
  __builtin_amdgcn_s_barrier();
  __builtin_amdgcn_sched_barrier(0);
  // tile 63
  GEMM_COMPUTE(As[ib1], Bs[ib1]);
  __syncthreads();                     // all LDS reads done before scratch aliases As

  // ---- K-half reduction: kh=1 waves park partials in LDS, kh=0 adds+stores.
  // Scratch aliases As[0] (16 KB): per tm-region 2048 floats (8 KB) -> 32 KB
  // total across As[0..1]; layout (mi*4+ni)*256 + lane*4, conflict-free.
  float* sc = (float*)&As[0][0];
  const int sbase = tm * 2048;
  if (kh == 1) {
#pragma unroll
    for (int mi = 0; mi < 2; ++mi)
#pragma unroll
      for (int ni = 0; ni < 4; ++ni)
        *(f32x4*)&sc[sbase + (mi * 4 + ni) * 256 + lane * 4] = acc[mi][ni];
  }
  __syncthreads();
  if (kh == 0) {
    // C/D layout (16x16): col = lane&15, row = quad*4 + reg (verified R1-R4)
#pragma unroll
    for (int mi = 0; mi < 2; ++mi)
#pragma unroll
      for (int ni = 0; ni < 4; ++ni) {
        f32x4 v = *(const f32x4*)&sc[sbase + (mi * 4 + ni) * 256 + lane * 4];
        acc[mi][ni] += v;
        const int r0 = m0 + tm * 32 + mi * 16 + quad * 4;
        const int c = n0 + ni * 16 + l15;
#pragma unroll
        for (int r = 0; r < 4; ++r)
          out[(size_t)(r0 + r) * NOUT + c] = fmaxf(acc[mi][ni][r], 0.0f);
      }
  }
}

extern "C" void kernel_launch(void* const* d_in, const int* in_sizes, int n_in,
                              void* d_out, int out_size, void* d_ws, size_t ws_size,
                              hipStream_t stream) {
  const float* x = (const float*)d_in[0];
  const float* W = (const float*)d_in[1];
  float* out = (float*)d_out;

  char* ws = (char*)d_ws;
  unsigned short* Am = (unsigned short*)(ws + AM_OFF);
  unsigned short* Wt = (unsigned short*)(ws + WT_OFF);
  double* partials = (double*)(ws + PART_OFF);
  float* thr = (float*)(ws + THR_OFF);

  haar1_kernel<<<NROWS + 2048, 256, 0, stream>>>(x, partials, W, Wt);
  thr_kernel<<<1, 1024, 0, stream>>>(partials, thr);
  haar2_kernel<<<NROWS, 256, 0, stream>>>(x, thr, Am);
  gemm_kernel<<<512, 512, 0, stream>>>(Am, Wt, out);
}